// Round 5
// baseline (893.823 us; speedup 1.0000x reference)
//
#include <hip/hip_runtime.h>
#include <stdint.h>

typedef __bf16 bf16;
typedef __bf16 bf16x4 __attribute__((ext_vector_type(4)));
typedef __bf16 bf16x8 __attribute__((ext_vector_type(8)));
typedef float floatx4 __attribute__((ext_vector_type(4)));
typedef short short4v __attribute__((ext_vector_type(4)));

#define HEADSZ 524288L  // 8192*64 elems per head per tensor

// 16x16x16 bf16 MFMA: D = A*B + C (A,B: 4 bf16/lane)
#if defined(__has_builtin)
#if __has_builtin(__builtin_amdgcn_mfma_f32_16x16x16bf16_1k)
#define HAVE_MFMA16_BUILTIN 1
#endif
#endif
__device__ __forceinline__ floatx4 mfma16(short4v a, short4v b, floatx4 c) {
#ifdef HAVE_MFMA16_BUILTIN
  return __builtin_amdgcn_mfma_f32_16x16x16bf16_1k(a, b, c, 0, 0, 0);
#else
  floatx4 d;
  asm("v_mfma_f32_16x16x16_bf16 %0, %1, %2, %3" : "=v"(d) : "v"(a), "v"(b), "v"(c));
  return d;
#endif
}

__device__ __forceinline__ void gload16(const bf16* g, bf16* l) {
  __builtin_amdgcn_global_load_lds(
      (const __attribute__((address_space(1))) uint8_t*)g,
      (__attribute__((address_space(3))) uint8_t*)l, 16, 0, 0);
}

// ---------------- dtype detect: 1 => inputs are fp32, 0 => bf16 ----------------
__global__ void detect_kernel(const unsigned short* __restrict__ x, int* __restrict__ flag) {
  int lane = threadIdx.x & 63;
  int cnt = 0;
#pragma unroll
  for (int i = 0; i < 4; ++i) {
    unsigned int u = x[2 * (lane * 4 + i)];
    float v = __uint_as_float(u << 16);
    if (!(fabsf(v) <= 1e4f)) cnt++;
  }
#pragma unroll
  for (int off = 1; off < 64; off <<= 1) cnt += __shfl_xor(cnt, off, 64);
  if (threadIdx.x == 0) *flag = (cnt > 32) ? 1 : 0;
}

// ---------------- ingest: canonicalize x + biases to bf16 ----------------
__global__ __launch_bounds__(256) void ingest_kernel(
    const void* s0, const void* s1, const void* s2,
    bf16* d0, bf16* d1, bf16* d2, const int* __restrict__ flag) {
  const long b0 = 6291456, b1 = b0 + 2304, b2 = b1 + 768;
  long g = ((long)blockIdx.x * 256 + threadIdx.x) * 8;
  if (g >= b2) return;
  const void* src; bf16* dst; long off;
  if (g < b0)      { src = s0; dst = d0; off = g; }
  else if (g < b1) { src = s1; dst = d1; off = g - b0; }
  else             { src = s2; dst = d2; off = g - b1; }
  if (*flag) {
    const float* s = (const float*)src + off;
#pragma unroll
    for (int e = 0; e < 8; ++e) dst[off + e] = (bf16)s[e];
  } else {
    *(uint4*)(dst + off) = *(const uint4*)((const bf16*)src + off);
  }
}

// ---------------- fused cast+transpose: in[R][C] -> out[C][R] bf16 ----------------
__global__ __launch_bounds__(256) void transposeW_kernel(
    const void* __restrict__ in, bf16* __restrict__ out, int R, int Ccols,
    const int* __restrict__ flag) {
  __shared__ bf16 t[32][33];
  int bx = blockIdx.x * 32, by = blockIdx.y * 32;
  int tx = threadIdx.x & 31, ty = threadIdx.x >> 5;
  const bool f32 = (*flag != 0);
#pragma unroll
  for (int i = ty; i < 32; i += 8) {
    long src = (long)(by + i) * Ccols + bx + tx;
    t[i][tx] = f32 ? (bf16)((const float*)in)[src] : ((const bf16*)in)[src];
  }
  __syncthreads();
#pragma unroll
  for (int i = ty; i < 32; i += 8) out[(long)(bx + i) * R + by + tx] = t[tx][i];
}

// ---------------- GEMM: C[M,N] = A[M,K] * BT[N,K]^T + bias ----------------
// tr-blocks compute the transposed C-tile (operand-swapped MFMA) so each lane's
// 4 acc values are 4 consecutive COLUMNS -> vector stores. V-scatter blocks keep
// normal orientation (4 consecutive tokens contiguous in V^T crumb).
template <int EPI>
__global__ __launch_bounds__(256, 2) void gemm_kernel(
    const bf16* __restrict__ A, const bf16* __restrict__ BT,
    const bf16* __restrict__ bias, void* __restrict__ Cout,
    int M, int N, int Kd, const int* __restrict__ flag) {
  __shared__ bf16 As[128 * 32];
  __shared__ bf16 Bs[128 * 32];
  const int tid = threadIdx.x;
  const int w = tid >> 6, lane = tid & 63;
  const int quad = lane >> 4, l15 = lane & 15;
  const int m0 = blockIdx.x * 128, n0 = blockIdx.y * 128;
  const int wm = w >> 1, wn = w & 1;
  const int srow = lane >> 2;
  const int scol = (lane & 3) * 8;

  const int which = (EPI == 1) ? (n0 / 768) : 0;
  const bool tr = (EPI == 0) || (which < 2);

  floatx4 acc[4][4] = {};
  const bf16* ga = A + (long)(m0 + 32 * w + srow) * Kd + scol;
  const bf16* gb = BT + (long)(n0 + 32 * w + srow) * Kd + scol;
  bf16* la = As + 32 * w * 32;
  bf16* lb = Bs + 32 * w * 32;

  for (int kk = 0; kk < Kd; kk += 32) {
    __syncthreads();
    gload16(ga + kk, la);
    gload16(ga + kk + 16 * Kd, la + 16 * 32);
    gload16(gb + kk, lb);
    gload16(gb + kk + 16 * Kd, lb + 16 * 32);
    __syncthreads();
    bf16x8 fa[4], fb[4];
#pragma unroll
    for (int i = 0; i < 4; ++i)
      fa[i] = *(const bf16x8*)(As + (64 * wm + 16 * i + l15) * 32 + quad * 8);
#pragma unroll
    for (int j = 0; j < 4; ++j)
      fb[j] = *(const bf16x8*)(Bs + (64 * wn + 16 * j + l15) * 32 + quad * 8);
    if (tr) {
#pragma unroll
      for (int i = 0; i < 4; ++i)
#pragma unroll
        for (int j = 0; j < 4; ++j)
          acc[i][j] = __builtin_amdgcn_mfma_f32_16x16x32_bf16(fb[j], fa[i], acc[i][j], 0, 0, 0);
    } else {
#pragma unroll
      for (int i = 0; i < 4; ++i)
#pragma unroll
        for (int j = 0; j < 4; ++j)
          acc[i][j] = __builtin_amdgcn_mfma_f32_16x16x32_bf16(fa[i], fb[j], acc[i][j], 0, 0, 0);
    }
  }

  const bool outf32 = (EPI == 0) && (flag[0] != 0);
  if (tr) {
    // value r -> col = col0 + r, row = m0+64wm+16i+l15
#pragma unroll
    for (int i = 0; i < 4; ++i) {
      const int row = m0 + 64 * wm + 16 * i + l15;
#pragma unroll
      for (int j = 0; j < 4; ++j) {
        const int col0 = n0 + 64 * wn + 16 * j + quad * 4;
        floatx4 v = acc[i][j];
#pragma unroll
        for (int r = 0; r < 4; ++r) v[r] += (float)bias[col0 + r];
        if (EPI == 1) {
          if (which == 0) {
#pragma unroll
            for (int r = 0; r < 4; ++r) v[r] *= 0.18033688011112042f;  // scale*log2e into Q
          }
          const int rem = col0 - which * 768;
          const int hh = rem >> 6, d0 = rem & 63;
          const long off = ((long)which * 12 + hh) * HEADSZ + (long)(row >> 6) * 4096 +
                           (d0 >> 3) * 512 + (row & 63) * 8 + (d0 & 7);
          bf16x4 bv;
#pragma unroll
          for (int r = 0; r < 4; ++r) bv[r] = (bf16)v[r];
          *(bf16x4*)((bf16*)Cout + off) = bv;
        } else {
          if (outf32) {
            *(floatx4*)((float*)Cout + (long)row * N + col0) = v;
          } else {
            bf16x4 bv;
#pragma unroll
            for (int r = 0; r < 4; ++r) bv[r] = (bf16)v[r];
            *(bf16x4*)((bf16*)Cout + (long)row * N + col0) = bv;
          }
        }
      }
    }
  } else {
    // V scatter: value r -> row = row0 + r (contiguous in V^T crumb), col fixed
#pragma unroll
    for (int i = 0; i < 4; ++i) {
      const int row0 = m0 + 64 * wm + 16 * i + quad * 4;
#pragma unroll
      for (int j = 0; j < 4; ++j) {
        const int col = n0 + 64 * wn + 16 * j + l15;
        const float bv = (float)bias[col];
        const int rem = col - 2 * 768;
        const int hh = rem >> 6, d = rem & 63;
        const long off = ((long)2 * 12 + hh) * HEADSZ + (long)(row0 >> 6) * 4096 +
                         ((row0 & 63) >> 3) * 512 + d * 8 + (row0 & 7);
        bf16x4 ov;
#pragma unroll
        for (int r = 0; r < 4; ++r) ov[r] = (bf16)(acc[i][j][r] + bv);
        *(bf16x4*)((bf16*)Cout + off) = ov;
      }
    }
  }
}

// ---------------- attention v5: (f, h, q-half) blocks, 512 threads ----------------
// 8 waves: g = w>>1 (64-q group of the 256-q half), kh = w&1 (64-key token-block of
// the 128-key chunk). K/V loaded 2x per (f,h) instead of 8x. Double-buffered 64KB.
// Register-direct P (16x16x16 PV). __launch_bounds__(512,4): combined regs <=128 so
// 2 blocks/CU (4 waves/SIMD) stay resident.
__global__ __launch_bounds__(512, 4) void attn_kernel(
    const bf16* __restrict__ qkv, const int* __restrict__ covis,
    bf16* __restrict__ attnout) {
  __shared__ bf16 db[2][16384];  // [buf][K 8192 | V 8192]

  const int tid = threadIdx.x;
  const int w = tid >> 6, lane = tid & 63;
  const int quad = lane >> 4, l15 = lane & 15;
  const int g = w >> 1, kh = w & 1;

  const int xcd = blockIdx.x & 7;
  const int idx = blockIdx.x >> 3;      // 0..47
  const int qhalf = idx & 1;
  const int fh = xcd * 24 + (idx >> 1); // fh = h*16 + f
  const int h = fh >> 4, f = fh & 15;
  const int qtb = f * 8 + qhalf * 4 + g;

  const bf16* qb = qkv + (long)(0 * 12 + h) * HEADSZ;
  const bf16* kb = qkv + (long)(1 * 12 + h) * HEADSZ;
  const bf16* vb = qkv + (long)(2 * 12 + h) * HEADSZ;

  int frames[6];
#pragma unroll
  for (int j = 0; j < 6; ++j) frames[j] = covis[f * 6 + j];

  // Q fragments (pre-scaled by GEMM epilogue): qa[s][nt] = Q[q=nt*16+l15][d=32s+quad*8..]
  bf16x8 qa[2][4];
  {
    const bf16* qblk = qb + (long)qtb * 4096;
#pragma unroll
    for (int s = 0; s < 2; ++s)
#pragma unroll
      for (int nt = 0; nt < 4; ++nt)
        qa[s][nt] = *(const bf16x8*)(qblk + (4 * s + quad) * 512 + (nt * 16 + l15) * 8);
  }

  floatx4 o[16] = {};  // o[mtd*4+nt] : O^T[d=mtd*16+quad*4+r][q=nt*16+l15]
  float rsum[4] = {0.f, 0.f, 0.f, 0.f};

  auto issue = [&](int c) {
    const int tb0 = frames[c >> 2] * 8 + (c & 3) * 2;
    const bf16* src = (w < 4 ? kb : vb) + (long)tb0 * 4096 + (w & 3) * 2048;
    bf16* dst = db[c & 1] + (w >= 4 ? 8192 : 0) + (w & 3) * 2048;
#pragma unroll
    for (int i = 0; i < 4; ++i) gload16(src + i * 512 + lane * 8, dst + i * 512);
  };

  issue(0);
  for (int c = 0; c < 24; ++c) {
    __syncthreads();           // buf[c&1] ready; buf[(c+1)&1] free
    if (c < 23) issue(c + 1);
    const bf16* Kb = db[c & 1] + kh * 4096;
    const bf16* Vb = db[c & 1] + 8192 + kh * 4096;

#pragma unroll
    for (int mt = 0; mt < 4; ++mt) {  // 16-key groups of the wave's 64 keys
      floatx4 st[4] = {};
#pragma unroll
      for (int s = 0; s < 2; ++s) {
        bf16x8 kf = *(const bf16x8*)(Kb + ((4 * s + quad) * 64 + mt * 16 + l15) * 8);
#pragma unroll
        for (int nt = 0; nt < 4; ++nt)
          st[nt] = __builtin_amdgcn_mfma_f32_16x16x32_bf16(kf, qa[s][nt], st[nt], 0, 0, 0);
      }
      short4v p[4];
#pragma unroll
      for (int nt = 0; nt < 4; ++nt) {
        bf16x4 pb;
#pragma unroll
        for (int r = 0; r < 4; ++r) {
          float e = __builtin_amdgcn_exp2f(st[nt][r]);
          pb[r] = (bf16)e;
          rsum[nt] += e;
        }
        p[nt] = __builtin_bit_cast(short4v, pb);
      }
#pragma unroll
      for (int mtd = 0; mtd < 4; ++mtd) {
        bf16x4 vf = *(const bf16x4*)(Vb + ((2 * mt + (quad >> 1)) * 64 + mtd * 16 + l15) * 8 +
                                     (quad & 1) * 4);
        short4v va = __builtin_bit_cast(short4v, vf);
#pragma unroll
        for (int nt = 0; nt < 4; ++nt)
          o[mtd * 4 + nt] = mfma16(va, p[nt], o[mtd * 4 + nt]);
      }
    }
  }

  // ---- epilogue ----
  // 1) full per-query sums: quad-reduce, then exchange across kh pair via LDS
  __syncthreads();
#pragma unroll
  for (int nt = 0; nt < 4; ++nt) {
    rsum[nt] += __shfl_xor(rsum[nt], 16, 64);
    rsum[nt] += __shfl_xor(rsum[nt], 32, 64);
  }
  float* sums = (float*)(&db[0][0]);  // 8*4*16 floats = 2KB
  if (quad == 0) {
#pragma unroll
    for (int nt = 0; nt < 4; ++nt) sums[((g * 2 + kh) * 4 + nt) * 16 + l15] = rsum[nt];
  }
  __syncthreads();
  float inv[4];
#pragma unroll
  for (int nt = 0; nt < 4; ++nt)
    inv[nt] = 1.0f / (rsum[nt] + sums[((g * 2 + (1 - kh)) * 4 + nt) * 16 + l15]);
  __syncthreads();

  // 2) kh=1 waves publish O^T partials (overwrites sums area - inv already in regs)
  float* scr = (float*)(&db[0][0]);  // 4 groups x 16KB = 64KB
  if (kh == 1) {
#pragma unroll
    for (int t = 0; t < 16; ++t) *(floatx4*)(scr + g * 4096 + (t * 64 + lane) * 4) = o[t];
  }
  __syncthreads();
  // 3) kh=0 waves combine, normalize, store
  if (kh == 0) {
#pragma unroll
    for (int mtd = 0; mtd < 4; ++mtd) {
#pragma unroll
      for (int nt = 0; nt < 4; ++nt) {
        const int t = mtd * 4 + nt;
        floatx4 v = o[t] + *(const floatx4*)(scr + g * 4096 + (t * 64 + lane) * 4);
        bf16x4 bv;
#pragma unroll
        for (int r = 0; r < 4; ++r) bv[r] = (bf16)(v[r] * inv[nt]);
        const long token = (long)qtb * 64 + nt * 16 + l15;
        *(bf16x4*)(attnout + token * 768 + h * 64 + mtd * 16 + quad * 4) = bv;
      }
    }
  }
}

extern "C" void kernel_launch(void* const* d_in, const int* in_sizes, int n_in,
                              void* d_out, int out_size, void* d_ws, size_t ws_size,
                              hipStream_t stream) {
  const void* x     = d_in[0];
  const void* Wqkv  = d_in[1];
  const void* bqkv  = d_in[2];
  const void* Wproj = d_in[3];
  const void* bproj = d_in[4];
  const int*  covis = (const int*)d_in[5];

  char* ws = (char*)d_ws;
  size_t off = 0;
  auto alloc = [&](size_t bytes) {
    char* p = ws + off;
    off += (bytes + 255) & ~(size_t)255;
    return p;
  };
  int*  flag   = (int*)alloc(256);
  bf16* xc     = (bf16*)alloc(6291456UL * 2);
  bf16* bqkvc  = (bf16*)alloc(2304UL * 2);
  bf16* bprojc = (bf16*)alloc(768UL * 2);
  bf16* WqkvT  = (bf16*)alloc(1769472UL * 2);
  bf16* WprojT = (bf16*)alloc(589824UL * 2);
  bf16* qkvws  = (bf16*)alloc(3UL * 12 * 8192 * 64 * 2);
  bf16* attnw  = (bf16*)alloc(6291456UL * 2);

  detect_kernel<<<1, 64, 0, stream>>>((const unsigned short*)x, flag);
  ingest_kernel<<<3074, 256, 0, stream>>>(x, bqkv, bproj, xc, bqkvc, bprojc, flag);
  transposeW_kernel<<<dim3(72, 24), 256, 0, stream>>>(Wqkv, WqkvT, 768, 2304, flag);
  transposeW_kernel<<<dim3(24, 24), 256, 0, stream>>>(Wproj, WprojT, 768, 768, flag);
  gemm_kernel<1><<<dim3(64, 18), 256, 0, stream>>>(xc, WqkvT, bqkvc, qkvws, 8192, 2304, 768, flag);
  attn_kernel<<<384, 512, 0, stream>>>(qkvws, covis, attnw);
  gemm_kernel<0><<<dim3(64, 6), 256, 0, stream>>>(attnw, WprojT, bprojc, d_out, 8192, 768, 768, flag);
}

// Round 6
// 309.879 us; speedup vs baseline: 2.8844x; 2.8844x over previous
//
#include <hip/hip_runtime.h>
#include <stdint.h>

typedef __bf16 bf16;
typedef __bf16 bf16x4 __attribute__((ext_vector_type(4)));
typedef __bf16 bf16x8 __attribute__((ext_vector_type(8)));
typedef float floatx4 __attribute__((ext_vector_type(4)));
typedef short short4v __attribute__((ext_vector_type(4)));

#define HEADSZ 524288L  // 8192*64 elems per head per tensor

// 16x16x16 bf16 MFMA: D = A*B + C (A,B: 4 bf16/lane)
#if defined(__has_builtin)
#if __has_builtin(__builtin_amdgcn_mfma_f32_16x16x16bf16_1k)
#define HAVE_MFMA16_BUILTIN 1
#endif
#endif
__device__ __forceinline__ floatx4 mfma16(short4v a, short4v b, floatx4 c) {
#ifdef HAVE_MFMA16_BUILTIN
  return __builtin_amdgcn_mfma_f32_16x16x16bf16_1k(a, b, c, 0, 0, 0);
#else
  floatx4 d;
  asm("v_mfma_f32_16x16x16_bf16 %0, %1, %2, %3" : "=v"(d) : "v"(a), "v"(b), "v"(c));
  return d;
#endif
}

__device__ __forceinline__ void gload16(const bf16* g, bf16* l) {
  __builtin_amdgcn_global_load_lds(
      (const __attribute__((address_space(1))) uint8_t*)g,
      (__attribute__((address_space(3))) uint8_t*)l, 16, 0, 0);
}

// ---------------- dtype detect: 1 => inputs are fp32, 0 => bf16 ----------------
__global__ void detect_kernel(const unsigned short* __restrict__ x, int* __restrict__ flag) {
  int lane = threadIdx.x & 63;
  int cnt = 0;
#pragma unroll
  for (int i = 0; i < 4; ++i) {
    unsigned int u = x[2 * (lane * 4 + i)];
    float v = __uint_as_float(u << 16);
    if (!(fabsf(v) <= 1e4f)) cnt++;
  }
#pragma unroll
  for (int off = 1; off < 64; off <<= 1) cnt += __shfl_xor(cnt, off, 64);
  if (threadIdx.x == 0) *flag = (cnt > 32) ? 1 : 0;
}

// ---------------- ingest: canonicalize x + biases to bf16 ----------------
__global__ __launch_bounds__(256) void ingest_kernel(
    const void* s0, const void* s1, const void* s2,
    bf16* d0, bf16* d1, bf16* d2, const int* __restrict__ flag) {
  const long b0 = 6291456, b1 = b0 + 2304, b2 = b1 + 768;
  long g = ((long)blockIdx.x * 256 + threadIdx.x) * 8;
  if (g >= b2) return;
  const void* src; bf16* dst; long off;
  if (g < b0)      { src = s0; dst = d0; off = g; }
  else if (g < b1) { src = s1; dst = d1; off = g - b0; }
  else             { src = s2; dst = d2; off = g - b1; }
  if (*flag) {
    const float* s = (const float*)src + off;
#pragma unroll
    for (int e = 0; e < 8; ++e) dst[off + e] = (bf16)s[e];
  } else {
    *(uint4*)(dst + off) = *(const uint4*)((const bf16*)src + off);
  }
}

// ---------------- fused cast+transpose: in[R][C] -> out[C][R] bf16 ----------------
__global__ __launch_bounds__(256) void transposeW_kernel(
    const void* __restrict__ in, bf16* __restrict__ out, int R, int Ccols,
    const int* __restrict__ flag) {
  __shared__ bf16 t[32][33];
  int bx = blockIdx.x * 32, by = blockIdx.y * 32;
  int tx = threadIdx.x & 31, ty = threadIdx.x >> 5;
  const bool f32 = (*flag != 0);
#pragma unroll
  for (int i = ty; i < 32; i += 8) {
    long src = (long)(by + i) * Ccols + bx + tx;
    t[i][tx] = f32 ? (bf16)((const float*)in)[src] : ((const bf16*)in)[src];
  }
  __syncthreads();
#pragma unroll
  for (int i = ty; i < 32; i += 8) out[(long)(bx + i) * R + by + tx] = t[tx][i];
}

// ---------------- GEMM: C[M,N] = A[M,K] * BT[N,K]^T + bias ----------------
template <int EPI>
__global__ __launch_bounds__(256, 2) void gemm_kernel(
    const bf16* __restrict__ A, const bf16* __restrict__ BT,
    const bf16* __restrict__ bias, void* __restrict__ Cout,
    int M, int N, int Kd, const int* __restrict__ flag) {
  __shared__ bf16 As[128 * 32];
  __shared__ bf16 Bs[128 * 32];
  const int tid = threadIdx.x;
  const int w = tid >> 6, lane = tid & 63;
  const int quad = lane >> 4, l15 = lane & 15;
  const int m0 = blockIdx.x * 128, n0 = blockIdx.y * 128;
  const int wm = w >> 1, wn = w & 1;
  const int srow = lane >> 2;
  const int scol = (lane & 3) * 8;

  const int which = (EPI == 1) ? (n0 / 768) : 0;
  const bool tr = (EPI == 0) || (which < 2);

  floatx4 acc[4][4] = {};
  const bf16* ga = A + (long)(m0 + 32 * w + srow) * Kd + scol;
  const bf16* gb = BT + (long)(n0 + 32 * w + srow) * Kd + scol;
  bf16* la = As + 32 * w * 32;
  bf16* lb = Bs + 32 * w * 32;

  for (int kk = 0; kk < Kd; kk += 32) {
    __syncthreads();
    gload16(ga + kk, la);
    gload16(ga + kk + 16 * Kd, la + 16 * 32);
    gload16(gb + kk, lb);
    gload16(gb + kk + 16 * Kd, lb + 16 * 32);
    __syncthreads();
    bf16x8 fa[4], fb[4];
#pragma unroll
    for (int i = 0; i < 4; ++i)
      fa[i] = *(const bf16x8*)(As + (64 * wm + 16 * i + l15) * 32 + quad * 8);
#pragma unroll
    for (int j = 0; j < 4; ++j)
      fb[j] = *(const bf16x8*)(Bs + (64 * wn + 16 * j + l15) * 32 + quad * 8);
    if (tr) {
#pragma unroll
      for (int i = 0; i < 4; ++i)
#pragma unroll
        for (int j = 0; j < 4; ++j)
          acc[i][j] = __builtin_amdgcn_mfma_f32_16x16x32_bf16(fb[j], fa[i], acc[i][j], 0, 0, 0);
    } else {
#pragma unroll
      for (int i = 0; i < 4; ++i)
#pragma unroll
        for (int j = 0; j < 4; ++j)
          acc[i][j] = __builtin_amdgcn_mfma_f32_16x16x32_bf16(fa[i], fb[j], acc[i][j], 0, 0, 0);
    }
  }

  const bool outf32 = (EPI == 0) && (flag[0] != 0);
  if (tr) {
#pragma unroll
    for (int i = 0; i < 4; ++i) {
      const int row = m0 + 64 * wm + 16 * i + l15;
#pragma unroll
      for (int j = 0; j < 4; ++j) {
        const int col0 = n0 + 64 * wn + 16 * j + quad * 4;
        floatx4 v = acc[i][j];
#pragma unroll
        for (int r = 0; r < 4; ++r) v[r] += (float)bias[col0 + r];
        if (EPI == 1) {
          if (which == 0) {
#pragma unroll
            for (int r = 0; r < 4; ++r) v[r] *= 0.18033688011112042f;  // scale*log2e into Q
          }
          const int rem = col0 - which * 768;
          const int hh = rem >> 6, d0 = rem & 63;
          const long off = ((long)which * 12 + hh) * HEADSZ + (long)(row >> 6) * 4096 +
                           (d0 >> 3) * 512 + (row & 63) * 8 + (d0 & 7);
          bf16x4 bv;
#pragma unroll
          for (int r = 0; r < 4; ++r) bv[r] = (bf16)v[r];
          *(bf16x4*)((bf16*)Cout + off) = bv;
        } else {
          if (outf32) {
            *(floatx4*)((float*)Cout + (long)row * N + col0) = v;
          } else {
            bf16x4 bv;
#pragma unroll
            for (int r = 0; r < 4; ++r) bv[r] = (bf16)v[r];
            *(bf16x4*)((bf16*)Cout + (long)row * N + col0) = bv;
          }
        }
      }
    }
  } else {
#pragma unroll
    for (int i = 0; i < 4; ++i) {
      const int row0 = m0 + 64 * wm + 16 * i + quad * 4;
#pragma unroll
      for (int j = 0; j < 4; ++j) {
        const int col = n0 + 64 * wn + 16 * j + l15;
        const float bv = (float)bias[col];
        const int rem = col - 2 * 768;
        const int hh = rem >> 6, d = rem & 63;
        const long off = ((long)2 * 12 + hh) * HEADSZ + (long)(row0 >> 6) * 4096 +
                         ((row0 & 63) >> 3) * 512 + d * 8 + (row0 & 7);
        bf16x4 ov;
#pragma unroll
        for (int r = 0; r < 4; ++r) ov[r] = (bf16)(acc[i][j][r] + bv);
        *(bf16x4*)((bf16*)Cout + off) = ov;
      }
    }
  }
}

// ---------------- attention v6: (f, h, q-half), 512 thr, NO-SPILL regs ----------------
// 8 waves: g = w>>1 (64-q group), kh = w&1 (64-key half of the 128-key chunk).
// K/V loaded 2x per (f,h). Double-buffered 64KB, single barrier per chunk.
// QK and PV both via 16x16x16 MFMA with bf16x4 fragments (qa = 16 regs).
// __launch_bounds__(512,2): 256-reg cap -> no scratch spill (R5 lesson: forcing
// 128 spilled o[] to scratch -> 1.7GB writes). 1 block/CU, 8 waves.
__global__ __launch_bounds__(512, 2) void attn_kernel(
    const bf16* __restrict__ qkv, const int* __restrict__ covis,
    bf16* __restrict__ attnout) {
  __shared__ bf16 db[2][16384];  // [buf][K 8192 | V 8192]

  const int tid = threadIdx.x;
  const int w = tid >> 6, lane = tid & 63;
  const int quad = lane >> 4, l15 = lane & 15;
  const int g = w >> 1, kh = w & 1;
  const int qh = quad >> 1, ql = quad & 1;  // crumb sub-addressing

  const int xcd = blockIdx.x & 7;
  const int idx = blockIdx.x >> 3;      // 0..47
  const int qhalf = idx & 1;
  const int fh = xcd * 24 + (idx >> 1); // fh = h*16 + f
  const int h = fh >> 4, f = fh & 15;
  const int qtb = f * 8 + qhalf * 4 + g;

  const bf16* qb = qkv + (long)(0 * 12 + h) * HEADSZ;
  const bf16* kb = qkv + (long)(1 * 12 + h) * HEADSZ;
  const bf16* vb = qkv + (long)(2 * 12 + h) * HEADSZ;

  int frames[6];
#pragma unroll
  for (int j = 0; j < 6; ++j) frames[j] = covis[f * 6 + j];

  // Q B-frags (pre-scaled): qa[s][nt] = Q[q=nt*16+l15][d=s*16+quad*4 .. +3]
  short4v qa[4][4];
  {
    const bf16* qblk = qb + (long)qtb * 4096;
#pragma unroll
    for (int s = 0; s < 4; ++s)
#pragma unroll
      for (int nt = 0; nt < 4; ++nt)
        qa[s][nt] = __builtin_bit_cast(short4v,
            *(const bf16x4*)(qblk + (s * 2 + qh) * 512 + (nt * 16 + l15) * 8 + ql * 4));
  }

  floatx4 o[16] = {};  // o[mtd*4+nt] : O^T[d=mtd*16+quad*4+r][q=nt*16+l15]
  float rsum[4] = {0.f, 0.f, 0.f, 0.f};

  auto issue = [&](int c) {
    const int tb0 = frames[c >> 2] * 8 + (c & 3) * 2;
    const bf16* src = (w < 4 ? kb : vb) + (long)tb0 * 4096 + (w & 3) * 2048;
    bf16* dst = db[c & 1] + (w >= 4 ? 8192 : 0) + (w & 3) * 2048;
#pragma unroll
    for (int i = 0; i < 4; ++i) gload16(src + i * 512 + lane * 8, dst + i * 512);
  };

  issue(0);
  for (int c = 0; c < 24; ++c) {
    __syncthreads();           // buf[c&1] ready; buf[(c+1)&1] free
    if (c < 23) issue(c + 1);
    const bf16* Kb = db[c & 1] + kh * 4096;
    const bf16* Vb = db[c & 1] + 8192 + kh * 4096;

#pragma unroll
    for (int mt = 0; mt < 4; ++mt) {  // 16-key groups of the wave's 64 keys
      floatx4 st[4] = {};
#pragma unroll
      for (int s = 0; s < 4; ++s) {
        // K A-frag: K[key=mt*16+l15][d=s*16+quad*4 .. +3]
        short4v kf = __builtin_bit_cast(short4v,
            *(const bf16x4*)(Kb + ((s * 2 + qh) * 64 + mt * 16 + l15) * 8 + ql * 4));
#pragma unroll
        for (int nt = 0; nt < 4; ++nt) st[nt] = mfma16(kf, qa[s][nt], st[nt]);
      }
      short4v p[4];
#pragma unroll
      for (int nt = 0; nt < 4; ++nt) {
        bf16x4 pb;
#pragma unroll
        for (int r = 0; r < 4; ++r) {
          float e = __builtin_amdgcn_exp2f(st[nt][r]);
          pb[r] = (bf16)e;
          rsum[nt] += e;
        }
        p[nt] = __builtin_bit_cast(short4v, pb);
      }
#pragma unroll
      for (int mtd = 0; mtd < 4; ++mtd) {
        // V^T A-frag: V[key=mt*16+quad*4 .. +3][d=mtd*16+l15]
        short4v va = __builtin_bit_cast(short4v,
            *(const bf16x4*)(Vb + ((2 * mt + qh) * 64 + mtd * 16 + l15) * 8 + ql * 4));
#pragma unroll
        for (int nt = 0; nt < 4; ++nt)
          o[mtd * 4 + nt] = mfma16(va, p[nt], o[mtd * 4 + nt]);
      }
    }
  }

  // ---- epilogue ----
  __syncthreads();
#pragma unroll
  for (int nt = 0; nt < 4; ++nt) {
    rsum[nt] += __shfl_xor(rsum[nt], 16, 64);
    rsum[nt] += __shfl_xor(rsum[nt], 32, 64);
  }
  float* sums = (float*)(&db[0][0]);
  if (quad == 0) {
#pragma unroll
    for (int nt = 0; nt < 4; ++nt) sums[((g * 2 + kh) * 4 + nt) * 16 + l15] = rsum[nt];
  }
  __syncthreads();
  float inv[4];
#pragma unroll
  for (int nt = 0; nt < 4; ++nt)
    inv[nt] = 1.0f / (rsum[nt] + sums[((g * 2 + (1 - kh)) * 4 + nt) * 16 + l15]);
  __syncthreads();

  float* scr = (float*)(&db[0][0]);  // 4 groups x 16KB = 64KB
  if (kh == 1) {
#pragma unroll
    for (int t = 0; t < 16; ++t) *(floatx4*)(scr + g * 4096 + (t * 64 + lane) * 4) = o[t];
  }
  __syncthreads();
  if (kh == 0) {
#pragma unroll
    for (int mtd = 0; mtd < 4; ++mtd) {
#pragma unroll
      for (int nt = 0; nt < 4; ++nt) {
        const int t = mtd * 4 + nt;
        floatx4 v = o[t] + *(const floatx4*)(scr + g * 4096 + (t * 64 + lane) * 4);
        bf16x4 bv;
#pragma unroll
        for (int r = 0; r < 4; ++r) bv[r] = (bf16)(v[r] * inv[nt]);
        const long token = (long)qtb * 64 + nt * 16 + l15;
        *(bf16x4*)(attnout + token * 768 + h * 64 + mtd * 16 + quad * 4) = bv;
      }
    }
  }
}

extern "C" void kernel_launch(void* const* d_in, const int* in_sizes, int n_in,
                              void* d_out, int out_size, void* d_ws, size_t ws_size,
                              hipStream_t stream) {
  const void* x     = d_in[0];
  const void* Wqkv  = d_in[1];
  const void* bqkv  = d_in[2];
  const void* Wproj = d_in[3];
  const void* bproj = d_in[4];
  const int*  covis = (const int*)d_in[5];

  char* ws = (char*)d_ws;
  size_t off = 0;
  auto alloc = [&](size_t bytes) {
    char* p = ws + off;
    off += (bytes + 255) & ~(size_t)255;
    return p;
  };
  int*  flag   = (int*)alloc(256);
  bf16* xc     = (bf16*)alloc(6291456UL * 2);
  bf16* bqkvc  = (bf16*)alloc(2304UL * 2);
  bf16* bprojc = (bf16*)alloc(768UL * 2);
  bf16* WqkvT  = (bf16*)alloc(1769472UL * 2);
  bf16* WprojT = (bf16*)alloc(589824UL * 2);
  bf16* qkvws  = (bf16*)alloc(3UL * 12 * 8192 * 64 * 2);
  bf16* attnw  = (bf16*)alloc(6291456UL * 2);

  detect_kernel<<<1, 64, 0, stream>>>((const unsigned short*)x, flag);
  ingest_kernel<<<3074, 256, 0, stream>>>(x, bqkv, bproj, xc, bqkvc, bprojc, flag);
  transposeW_kernel<<<dim3(72, 24), 256, 0, stream>>>(Wqkv, WqkvT, 768, 2304, flag);
  transposeW_kernel<<<dim3(24, 24), 256, 0, stream>>>(Wproj, WprojT, 768, 768, flag);
  gemm_kernel<1><<<dim3(64, 18), 256, 0, stream>>>(xc, WqkvT, bqkvc, qkvws, 8192, 2304, 768, flag);
  attn_kernel<<<384, 512, 0, stream>>>(qkvws, covis, attnw);
  gemm_kernel<0><<<dim3(64, 6), 256, 0, stream>>>(attnw, WprojT, bprojc, d_out, 8192, 768, 768, flag);
}

// Round 7
// 251.375 us; speedup vs baseline: 3.5557x; 1.2327x over previous
//
#include <hip/hip_runtime.h>
#include <stdint.h>

typedef __bf16 bf16;
typedef __bf16 bf16x4 __attribute__((ext_vector_type(4)));
typedef __bf16 bf16x8 __attribute__((ext_vector_type(8)));
typedef float floatx4 __attribute__((ext_vector_type(4)));

#define HEADSZ 524288L  // 8192*64 elems per head per tensor

__device__ __forceinline__ void gload16(const bf16* g, bf16* l) {
  __builtin_amdgcn_global_load_lds(
      (const __attribute__((address_space(1))) uint8_t*)g,
      (__attribute__((address_space(3))) uint8_t*)l, 16, 0, 0);
}

// ---------------- fused prep: dtype-detect (per block, deterministic) +
// ingest x/biases + both weight transposes + flag publish ----------------
__global__ __launch_bounds__(256) void prep_kernel(
    const void* __restrict__ x, const void* __restrict__ Wqkv,
    const void* __restrict__ bqkv, const void* __restrict__ Wproj,
    const void* __restrict__ bproj,
    bf16* __restrict__ xc, bf16* __restrict__ WqkvT,
    bf16* __restrict__ bqkvc, bf16* __restrict__ bprojc,
    bf16* __restrict__ WprojT, int* __restrict__ flag) {
  __shared__ int sflag;
  __shared__ bf16 t[32][33];
  const int tid = threadIdx.x;
  // local detect: fp32 mantissa halves viewed as bf16 are huge/inf/nan ~45%
  if (tid < 64) {
    int cnt = 0;
#pragma unroll
    for (int i = 0; i < 4; ++i) {
      unsigned int u = ((const unsigned short*)x)[2 * (tid * 4 + i)];
      float v = __uint_as_float(u << 16);
      if (!(fabsf(v) <= 1e4f)) cnt++;
    }
#pragma unroll
    for (int off = 1; off < 64; off <<= 1) cnt += __shfl_xor(cnt, off, 64);
    if (tid == 0) sflag = (cnt > 32) ? 1 : 0;
  }
  __syncthreads();
  const bool f32 = (sflag != 0);
  const int bid = blockIdx.x;

  auto dotr = [&](const void* in, bf16* out, int R, int Ccols, int bx, int by) {
    int tx = tid & 31, ty = tid >> 5;
#pragma unroll
    for (int i = ty; i < 32; i += 8) {
      long src = (long)(by + i) * Ccols + bx + tx;
      t[i][tx] = f32 ? (bf16)((const float*)in)[src] : ((const bf16*)in)[src];
    }
    __syncthreads();
#pragma unroll
    for (int i = ty; i < 32; i += 8) out[(long)(bx + i) * R + by + tx] = t[tx][i];
  };

  if (bid < 3072) {  // xc: 6291456 elems
    long g = ((long)bid * 256 + tid) * 8;
    if (f32) {
      const float* s = (const float*)x + g;
#pragma unroll
      for (int e = 0; e < 8; ++e) xc[g + e] = (bf16)s[e];
    } else {
      *(uint4*)(xc + g) = *(const uint4*)((const bf16*)x + g);
    }
  } else if (bid < 3074) {  // biases (2304 + 768) + flag
    if (bid == 3072 && tid == 0) *flag = f32 ? 1 : 0;
    long g = (long)(bid - 3072) * 2048 + tid * 8;
    if (g < 3072) {
      const void* src; bf16* dst; long off;
      if (g < 2304) { src = bqkv; dst = bqkvc; off = g; }
      else          { src = bproj; dst = bprojc; off = g - 2304; }
      if (f32) {
        const float* s = (const float*)src + off;
#pragma unroll
        for (int e = 0; e < 8; ++e) dst[off + e] = (bf16)s[e];
      } else {
        *(uint4*)(dst + off) = *(const uint4*)((const bf16*)src + off);
      }
    }
  } else if (bid < 4802) {  // WqkvT: 72 x 24 tiles (R=768, C=2304)
    int ti = bid - 3074;
    dotr(Wqkv, WqkvT, 768, 2304, (ti % 72) * 32, (ti / 72) * 32);
  } else {  // WprojT: 24 x 24 tiles (R=768, C=768)
    int ti = bid - 4802;
    dotr(Wproj, WprojT, 768, 768, (ti % 24) * 32, (ti / 24) * 32);
  }
}

// ---------------- GEMM: C[M,N] = A[M,K] * BT[N,K]^T + bias ----------------
template <int EPI>
__global__ __launch_bounds__(256, 2) void gemm_kernel(
    const bf16* __restrict__ A, const bf16* __restrict__ BT,
    const bf16* __restrict__ bias, void* __restrict__ Cout,
    int M, int N, int Kd, const int* __restrict__ flag) {
  __shared__ bf16 As[128 * 32];
  __shared__ bf16 Bs[128 * 32];
  const int tid = threadIdx.x;
  const int w = tid >> 6, lane = tid & 63;
  const int quad = lane >> 4, l15 = lane & 15;
  const int m0 = blockIdx.x * 128, n0 = blockIdx.y * 128;
  const int wm = w >> 1, wn = w & 1;
  const int srow = lane >> 2;
  const int scol = (lane & 3) * 8;

  const int which = (EPI == 1) ? (n0 / 768) : 0;
  const bool tr = (EPI == 0) || (which < 2);

  floatx4 acc[4][4] = {};
  const bf16* ga = A + (long)(m0 + 32 * w + srow) * Kd + scol;
  const bf16* gb = BT + (long)(n0 + 32 * w + srow) * Kd + scol;
  bf16* la = As + 32 * w * 32;
  bf16* lb = Bs + 32 * w * 32;

  for (int kk = 0; kk < Kd; kk += 32) {
    __syncthreads();
    gload16(ga + kk, la);
    gload16(ga + kk + 16 * Kd, la + 16 * 32);
    gload16(gb + kk, lb);
    gload16(gb + kk + 16 * Kd, lb + 16 * 32);
    __syncthreads();
    bf16x8 fa[4], fb[4];
#pragma unroll
    for (int i = 0; i < 4; ++i)
      fa[i] = *(const bf16x8*)(As + (64 * wm + 16 * i + l15) * 32 + quad * 8);
#pragma unroll
    for (int j = 0; j < 4; ++j)
      fb[j] = *(const bf16x8*)(Bs + (64 * wn + 16 * j + l15) * 32 + quad * 8);
    if (tr) {
#pragma unroll
      for (int i = 0; i < 4; ++i)
#pragma unroll
        for (int j = 0; j < 4; ++j)
          acc[i][j] = __builtin_amdgcn_mfma_f32_16x16x32_bf16(fb[j], fa[i], acc[i][j], 0, 0, 0);
    } else {
#pragma unroll
      for (int i = 0; i < 4; ++i)
#pragma unroll
        for (int j = 0; j < 4; ++j)
          acc[i][j] = __builtin_amdgcn_mfma_f32_16x16x32_bf16(fa[i], fb[j], acc[i][j], 0, 0, 0);
    }
  }

  const bool outf32 = (EPI == 0) && (flag[0] != 0);
  if (tr) {
#pragma unroll
    for (int i = 0; i < 4; ++i) {
      const int row = m0 + 64 * wm + 16 * i + l15;
#pragma unroll
      for (int j = 0; j < 4; ++j) {
        const int col0 = n0 + 64 * wn + 16 * j + quad * 4;
        floatx4 v = acc[i][j];
#pragma unroll
        for (int r = 0; r < 4; ++r) v[r] += (float)bias[col0 + r];
        if (EPI == 1) {
          if (which == 0) {
#pragma unroll
            for (int r = 0; r < 4; ++r) v[r] *= 0.18033688011112042f;  // scale*log2e into Q
          }
          const int rem = col0 - which * 768;
          const int hh = rem >> 6, d0 = rem & 63;
          const long off = ((long)which * 12 + hh) * HEADSZ + (long)(row >> 6) * 4096 +
                           (d0 >> 3) * 512 + (row & 63) * 8 + (d0 & 7);
          bf16x4 bv;
#pragma unroll
          for (int r = 0; r < 4; ++r) bv[r] = (bf16)v[r];
          *(bf16x4*)((bf16*)Cout + off) = bv;
        } else {
          if (outf32) {
            *(floatx4*)((float*)Cout + (long)row * N + col0) = v;
          } else {
            bf16x4 bv;
#pragma unroll
            for (int r = 0; r < 4; ++r) bv[r] = (bf16)v[r];
            *(bf16x4*)((bf16*)Cout + (long)row * N + col0) = bv;
          }
        }
      }
    }
  } else {
#pragma unroll
    for (int i = 0; i < 4; ++i) {
      const int row0 = m0 + 64 * wm + 16 * i + quad * 4;
#pragma unroll
      for (int j = 0; j < 4; ++j) {
        const int col = n0 + 64 * wn + 16 * j + l15;
        const float bv = (float)bias[col];
        const int rem = col - 2 * 768;
        const int hh = rem >> 6, d = rem & 63;
        const long off = ((long)2 * 12 + hh) * HEADSZ + (long)(row0 >> 6) * 4096 +
                         ((row0 & 63) >> 3) * 512 + d * 8 + (row0 & 7);
        bf16x4 ov;
#pragma unroll
        for (int r = 0; r < 4; ++r) ov[r] = (bf16)(acc[i][j][r] + bv);
        *(bf16x4*)((bf16*)Cout + off) = ov;
      }
    }
  }
}

// ---------------- attention v7: full-rate MFMA everywhere ----------------
// 768 blocks = (fh 192) x (q-quarter 4); 256 thr = 4 waves (qg2 x kh2).
// Wave: 64 q x 64 keys per 128-key chunk. QK: 16x16x32. PV: 16x16x32 with
// PERMUTED K - concat two adjacent 16-key P C-tiles as B (keys quad*4+r per
// half) and read the matching two b64 V^T frags as A; permutation identical
// on both operands so the contraction is exact. Zero LDS round-trip for P.
// Double-buffered 64KB, one barrier per chunk. 2 blocks resident/CU, 3 work.
__global__ __launch_bounds__(256, 2) void attn_kernel(
    const bf16* __restrict__ qkv, const int* __restrict__ covis,
    bf16* __restrict__ attnout) {
  __shared__ bf16 db[2][16384];  // [buf][K 8192 | V 8192] elems (128 keys)

  const int tid = threadIdx.x;
  const int w = tid >> 6, lane = tid & 63;
  const int quad = lane >> 4, l15 = lane & 15;
  const int qg = w >> 1, kh = w & 1;
  const int qh = quad >> 1, ql = quad & 1;

  // swizzle: 96 blocks per XCD = 24 fh x 4 qq; consecutive idx share fh (L2 reuse)
  const int xcd = blockIdx.x & 7;
  const int idx = blockIdx.x >> 3;       // 0..95
  const int qq = idx & 3;
  const int fh = xcd * 24 + (idx >> 2);  // fh = h*16 + f
  const int h = fh >> 4, f = fh & 15;
  const int qtb = f * 8 + qq * 2 + qg;

  const bf16* qb = qkv + (long)(0 * 12 + h) * HEADSZ;
  const bf16* kb = qkv + (long)(1 * 12 + h) * HEADSZ;
  const bf16* vb = qkv + (long)(2 * 12 + h) * HEADSZ;

  int frames[6];
#pragma unroll
  for (int j = 0; j < 6; ++j) frames[j] = covis[f * 6 + j];

  // Q B-frags (pre-scaled): qa[s][nt] = Q[q=nt*16+l15][d = s*32 + quad*8 + j]
  bf16x8 qa[2][4];
  {
    const bf16* qblk = qb + (long)qtb * 4096;
#pragma unroll
    for (int s = 0; s < 2; ++s)
#pragma unroll
      for (int nt = 0; nt < 4; ++nt)
        qa[s][nt] = *(const bf16x8*)(qblk + (4 * s + quad) * 512 + (nt * 16 + l15) * 8);
  }

  floatx4 o[16] = {};  // o[mtd*4+nt] : O^T[d=mtd*16+quad*4+r][q=nt*16+l15]
  float rsum[4] = {0.f, 0.f, 0.f, 0.f};

  auto issue = [&](int c) {
    const int tb0 = frames[c >> 2] * 8 + (c & 3) * 2;
    const bf16* src = (w < 2 ? kb : vb) + (long)tb0 * 4096 + (w & 1) * 4096;
    bf16* dst = db[c & 1] + (w < 2 ? 0 : 8192) + (w & 1) * 4096;
#pragma unroll
    for (int i = 0; i < 8; ++i) gload16(src + i * 512 + lane * 8, dst + i * 512);
  };

  issue(0);
  for (int c = 0; c < 24; ++c) {
    __syncthreads();           // buf[c&1] ready; buf[(c+1)&1] free
    if (c < 23) issue(c + 1);
    const bf16* Kb = db[c & 1] + kh * 4096;
    const bf16* Vb = db[c & 1] + 8192 + kh * 4096;

#pragma unroll
    for (int pair = 0; pair < 2; ++pair) {  // 32-key windows of the wave's 64
      bf16x4 p2[2][4];
#pragma unroll
      for (int half = 0; half < 2; ++half) {
        const int mt = pair * 2 + half;
        floatx4 st[4] = {};
#pragma unroll
        for (int s = 0; s < 2; ++s) {
          bf16x8 kf = *(const bf16x8*)(Kb + ((4 * s + quad) * 64 + mt * 16 + l15) * 8);
#pragma unroll
          for (int nt = 0; nt < 4; ++nt)
            st[nt] = __builtin_amdgcn_mfma_f32_16x16x32_bf16(kf, qa[s][nt], st[nt], 0, 0, 0);
        }
#pragma unroll
        for (int nt = 0; nt < 4; ++nt) {
#pragma unroll
          for (int r = 0; r < 4; ++r) {
            float e = __builtin_amdgcn_exp2f(st[nt][r]);
            p2[half][nt][r] = (bf16)e;
            rsum[nt] += e;
          }
        }
      }
      // PV, permuted-K K=32: A = V^T keys [pair*32+quad*4.. , pair*32+16+quad*4..]
#pragma unroll
      for (int mtd = 0; mtd < 4; ++mtd) {
        bf16x4 vlo = *(const bf16x4*)(Vb + ((4 * pair + qh) * 64 + mtd * 16 + l15) * 8 + ql * 4);
        bf16x4 vhi = *(const bf16x4*)(Vb + ((4 * pair + 2 + qh) * 64 + mtd * 16 + l15) * 8 + ql * 4);
        bf16x8 va;
#pragma unroll
        for (int e = 0; e < 4; ++e) { va[e] = vlo[e]; va[4 + e] = vhi[e]; }
#pragma unroll
        for (int nt = 0; nt < 4; ++nt) {
          bf16x8 pb;
#pragma unroll
          for (int e = 0; e < 4; ++e) { pb[e] = p2[0][nt][e]; pb[4 + e] = p2[1][nt][e]; }
          o[mtd * 4 + nt] = __builtin_amdgcn_mfma_f32_16x16x32_bf16(va, pb, o[mtd * 4 + nt], 0, 0, 0);
        }
      }
    }
  }

  // ---- epilogue: combine kh pair ----
#pragma unroll
  for (int nt = 0; nt < 4; ++nt) {
    rsum[nt] += __shfl_xor(rsum[nt], 16, 64);
    rsum[nt] += __shfl_xor(rsum[nt], 32, 64);
  }
  __syncthreads();
  float* sums = (float*)(&db[0][0]);  // 4*4*16 floats
  if (quad == 0) {
#pragma unroll
    for (int nt = 0; nt < 4; ++nt) sums[((qg * 2 + kh) * 4 + nt) * 16 + l15] = rsum[nt];
  }
  __syncthreads();
  float inv[4];
#pragma unroll
  for (int nt = 0; nt < 4; ++nt)
    inv[nt] = 1.0f / (rsum[nt] + sums[((qg * 2 + (1 - kh)) * 4 + nt) * 16 + l15]);
  __syncthreads();

  float* scr = (float*)(&db[0][0]);  // per qg 16KB -> 32KB total
  if (kh == 1) {
#pragma unroll
    for (int t = 0; t < 16; ++t) *(floatx4*)(scr + qg * 4096 + (t * 64 + lane) * 4) = o[t];
  }
  __syncthreads();
  if (kh == 0) {
#pragma unroll
    for (int mtd = 0; mtd < 4; ++mtd) {
#pragma unroll
      for (int nt = 0; nt < 4; ++nt) {
        const int t = mtd * 4 + nt;
        floatx4 v = o[t] + *(const floatx4*)(scr + qg * 4096 + (t * 64 + lane) * 4);
        bf16x4 bv;
#pragma unroll
        for (int r = 0; r < 4; ++r) bv[r] = (bf16)(v[r] * inv[nt]);
        const long token = (long)qtb * 64 + nt * 16 + l15;
        *(bf16x4*)(attnout + token * 768 + h * 64 + mtd * 16 + quad * 4) = bv;
      }
    }
  }
}

extern "C" void kernel_launch(void* const* d_in, const int* in_sizes, int n_in,
                              void* d_out, int out_size, void* d_ws, size_t ws_size,
                              hipStream_t stream) {
  const void* x     = d_in[0];
  const void* Wqkv  = d_in[1];
  const void* bqkv  = d_in[2];
  const void* Wproj = d_in[3];
  const void* bproj = d_in[4];
  const int*  covis = (const int*)d_in[5];

  char* ws = (char*)d_ws;
  size_t off = 0;
  auto alloc = [&](size_t bytes) {
    char* p = ws + off;
    off += (bytes + 255) & ~(size_t)255;
    return p;
  };
  int*  flag   = (int*)alloc(256);
  bf16* xc     = (bf16*)alloc(6291456UL * 2);
  bf16* bqkvc  = (bf16*)alloc(2304UL * 2);
  bf16* bprojc = (bf16*)alloc(768UL * 2);
  bf16* WqkvT  = (bf16*)alloc(1769472UL * 2);
  bf16* WprojT = (bf16*)alloc(589824UL * 2);
  bf16* qkvws  = (bf16*)alloc(3UL * 12 * 8192 * 64 * 2);
  bf16* attnw  = (bf16*)alloc(6291456UL * 2);

  prep_kernel<<<5378, 256, 0, stream>>>(x, Wqkv, bqkv, Wproj, bproj,
                                        xc, WqkvT, bqkvc, bprojc, WprojT, flag);
  gemm_kernel<1><<<dim3(64, 18), 256, 0, stream>>>(xc, WqkvT, bqkvc, qkvws, 8192, 2304, 768, flag);
  attn_kernel<<<768, 256, 0, stream>>>(qkvws, covis, attnw);
  gemm_kernel<0><<<dim3(64, 6), 256, 0, stream>>>(attnw, WprojT, bprojc, d_out, 8192, 768, 768, flag);
}